// Round 2
// 632.263 us; speedup vs baseline: 1.0422x; 1.0422x over previous
//
#include <hip/hip_runtime.h>
#include <hip/hip_bf16.h>

#define NUSERS 100000
#define NITEMS 50000
#define NNODES 150000
#define EMB 64
#define NLAYERS 3
#define NEDGES 2400000
#define SCAN_ITEMS 1024
#define NSCAN_BLOCKS ((NNODES + SCAN_ITEMS - 1) / SCAN_ITEMS)   // 147
#define NTILES (NNODES / 16)                                    // 9375

typedef __attribute__((ext_vector_type(8))) short short8;
typedef __attribute__((ext_vector_type(4))) float float4v;

__device__ __forceinline__ float bf2f(unsigned short u) {
    return __uint_as_float((unsigned int)u << 16);
}
__device__ __forceinline__ unsigned short f2bf(float f) {
    unsigned int x = __float_as_uint(f);
    return (unsigned short)((x + 0x7FFFu + ((x >> 16) & 1u)) >> 16);   // RNE
}

// ---------- CSR build (once; adjacency identical for all layers) ----------
// NOTE: single atomic pass by design. Measured: 2.4M device-scope atomics run at
// ~10/cycle chip-wide (hist_rank 101us, WRITE_SIZE ~86MB = 32B write-through per
// atomic). Do NOT add a second atomic pass (e.g. rank-in-scatter) — it doubles
// the wall. Next-round candidate: radix-sort-based build.

__global__ __launch_bounds__(256) void hist_rank_kernel(
    const int* __restrict__ rows, int* __restrict__ deg, int* __restrict__ rank)
{
    int e = blockIdx.x * 256 + threadIdx.x;
    if (e >= NEDGES) return;
    rank[e] = atomicAdd(&deg[rows[e]], 1);
}

__global__ __launch_bounds__(256) void block_sum_kernel(
    const int* __restrict__ deg, int* __restrict__ bsum)
{
    __shared__ int lds[256];
    int t = threadIdx.x;
    int base = blockIdx.x * SCAN_ITEMS + t * 4;
    int s = 0;
    #pragma unroll
    for (int k = 0; k < 4; ++k) {
        int idx = base + k;
        s += (idx < NNODES) ? deg[idx] : 0;
    }
    lds[t] = s; __syncthreads();
    for (int off = 128; off; off >>= 1) {
        if (t < off) lds[t] += lds[t + off];
        __syncthreads();
    }
    if (t == 0) bsum[blockIdx.x] = lds[0];
}

__global__ __launch_bounds__(256) void scan_partials_kernel(
    const int* __restrict__ bsum, int* __restrict__ bscan, int* __restrict__ rowptr)
{
    __shared__ int lds[256];
    int t = threadIdx.x;
    int v = (t < NSCAN_BLOCKS) ? bsum[t] : 0;
    lds[t] = v; __syncthreads();
    for (int off = 1; off < 256; off <<= 1) {
        int add = (t >= off) ? lds[t - off] : 0;
        __syncthreads();
        lds[t] += add;
        __syncthreads();
    }
    if (t < NSCAN_BLOCKS) bscan[t] = lds[t] - v;
    if (t == 0) rowptr[NNODES] = NEDGES;
}

__global__ __launch_bounds__(256) void block_scan_kernel(
    const int* __restrict__ deg, const int* __restrict__ bscan,
    int* __restrict__ rowptr)
{
    __shared__ int lds[256];
    int t = threadIdx.x;
    int base = blockIdx.x * SCAN_ITEMS + t * 4;
    int d[4]; int s = 0;
    #pragma unroll
    for (int k = 0; k < 4; ++k) {
        int idx = base + k;
        d[k] = (idx < NNODES) ? deg[idx] : 0;
        s += d[k];
    }
    lds[t] = s; __syncthreads();
    int v = s;
    for (int off = 1; off < 256; off <<= 1) {
        int add = (t >= off) ? lds[t - off] : 0;
        __syncthreads();
        lds[t] += add;
        __syncthreads();
    }
    int ex = lds[t] - v + bscan[blockIdx.x];
    #pragma unroll
    for (int k = 0; k < 4; ++k) {
        int idx = base + k;
        if (idx < NNODES) { rowptr[idx] = ex; ex += d[k]; }
    }
}

__global__ __launch_bounds__(256) void scatter_kernel(
    const int* __restrict__ rows, const int* __restrict__ cols,
    const float* __restrict__ vals, const int* __restrict__ rank,
    const int* __restrict__ rowptr, int2* __restrict__ edges)
{
    int e = blockIdx.x * 256 + threadIdx.x;
    if (e >= NEDGES) return;
    int pos = rowptr[rows[e]] + rank[e];
    edges[pos] = make_int2(cols[e], __float_as_int(vals[e]));
}

// ---------- weight fp32 -> bf16, TRANSPOSED to [layer][n][k] (once) ----------
// Transposed storage makes dense_mfma's B-fragment a contiguous short8 load
// (16 x 16B loads/wave instead of 128 scalar ushort loads/wave).
__global__ __launch_bounds__(256) void wconv_kernel(
    const float* __restrict__ gw, const float* __restrict__ bw,
    unsigned short* __restrict__ wg_bf, unsigned short* __restrict__ wb_bf)
{
    int i = blockIdx.x * 256 + threadIdx.x;
    if (i >= NLAYERS * EMB * EMB) return;
    int l = i >> 12;            // / (EMB*EMB)
    int k = (i >> 6) & 63;
    int n = i & 63;
    int o = (l << 12) | (n << 6) | k;   // [l][n][k]
    wg_bf[o] = f2bf(gw[i]);
    wb_bf[o] = f2bf(bw[i]);
}

// ---------- ego init (bf16) + output cols 0..63 (fp32) ----------
__global__ __launch_bounds__(256) void init_kernel(
    const float* __restrict__ ue, const float* __restrict__ ie,
    unsigned short* __restrict__ ego_bf, float* __restrict__ out)
{
    int i = blockIdx.x * 256 + threadIdx.x;   // float4 index over NNODES*16
    if (i >= NNODES * 16) return;
    int n = i >> 4, q = i & 15;
    float4 v = (n < NUSERS) ? ((const float4*)ue)[i]
                            : ((const float4*)ie)[i - NUSERS * 16];
    *(float4*)(out + (size_t)n * 256 + q * 4) = v;
    ushort4 b;
    b.x = f2bf(v.x); b.y = f2bf(v.y); b.z = f2bf(v.z); b.w = f2bf(v.w);
    *(ushort4*)(ego_bf + (size_t)n * EMB + q * 4) = b;
}

// ---------- pull-mode SpMM: side = A @ ego ----------
// One row per 16-lane quarter-wave; lane cp owns cols cp*4..cp*4+3 (uint2 = 8B
// gather). Edge (col,val) read directly by all 16 lanes (same-address broadcast,
// L1/L2 hit) — ZERO shuffles, zero epilogue reduction (each lane fully owns its
// columns). Per edge: 0.5 wave-VMEM, 0 DS (was ~1 VMEM ushort + 2 ds_bpermute).
__global__ __launch_bounds__(256) void spmm_pull(
    const int* __restrict__ rowptr, const int2* __restrict__ edges,
    const unsigned short* __restrict__ ego_bf, unsigned short* __restrict__ side_bf)
{
    const int t  = threadIdx.x;
    const int cp = t & 15;                       // col-chunk: cols cp*4..cp*4+3
    const int r  = blockIdx.x * 16 + (t >> 4);   // 16 rows/block, 4/wave
    const int s = rowptr[r], e = rowptr[r + 1];

    float a0 = 0.f, a1 = 0.f, a2 = 0.f, a3 = 0.f;
    float b0 = 0.f, b1 = 0.f, b2 = 0.f, b3 = 0.f;
    int i = s;
    for (; i + 2 <= e; i += 2) {                 // 2 edges in flight (4 loads)
        int2 e0 = edges[i];
        int2 e1 = edges[i + 1];
        float v0 = __int_as_float(e0.y);
        float v1 = __int_as_float(e1.y);
        uint2 u0 = *(const uint2*)(ego_bf + (size_t)e0.x * EMB + cp * 4);
        uint2 u1 = *(const uint2*)(ego_bf + (size_t)e1.x * EMB + cp * 4);
        a0 += v0 * __uint_as_float(u0.x << 16);
        a1 += v0 * __uint_as_float(u0.x & 0xffff0000u);
        a2 += v0 * __uint_as_float(u0.y << 16);
        a3 += v0 * __uint_as_float(u0.y & 0xffff0000u);
        b0 += v1 * __uint_as_float(u1.x << 16);
        b1 += v1 * __uint_as_float(u1.x & 0xffff0000u);
        b2 += v1 * __uint_as_float(u1.y << 16);
        b3 += v1 * __uint_as_float(u1.y & 0xffff0000u);
    }
    if (i < e) {
        int2 e0 = edges[i];
        float v0 = __int_as_float(e0.y);
        uint2 u0 = *(const uint2*)(ego_bf + (size_t)e0.x * EMB + cp * 4);
        a0 += v0 * __uint_as_float(u0.x << 16);
        a1 += v0 * __uint_as_float(u0.x & 0xffff0000u);
        a2 += v0 * __uint_as_float(u0.y << 16);
        a3 += v0 * __uint_as_float(u0.y & 0xffff0000u);
    }
    a0 += b0; a1 += b1; a2 += b2; a3 += b3;

    ushort4 o;
    o.x = f2bf(a0); o.y = f2bf(a1); o.z = f2bf(a2); o.w = f2bf(a3);
    *(ushort4*)(side_bf + (size_t)r * EMB + cp * 4) = o;
}

// ---------- MFMA dense: leaky(S@Wg+bg) + leaky((E*S)@Wb+bb), update ego, normalize ----------
// One wave per 16-row tile. 16x16x32 bf16 MFMA:
//   A[m=lane&15][k=(lane>>4)*8+j]; C/D: col=lane&15, row=(lane>>4)*4+reg.
// Weights arrive TRANSPOSED [n][k]: B-fragment = contiguous short8 load.
__global__ __launch_bounds__(256) void dense_mfma(
    const unsigned short* __restrict__ side_bf, unsigned short* __restrict__ ego_bf,
    const unsigned short* __restrict__ wg_bf, const unsigned short* __restrict__ wb_bf,
    const float* __restrict__ gb, const float* __restrict__ bb,
    float* __restrict__ out, int out_col0)
{
    const int lane = threadIdx.x & 63;
    const int w    = threadIdx.x >> 6;
    const int m    = lane & 15;     // row (A) / col (B, C)
    const int q    = lane >> 4;     // quad

    const int t = (int)blockIdx.x * 4 + w;     // 16-row tile index
    if (t >= NTILES) return;

    // ---- B fragments: [n0][kh], lane j holds B[k=kh*32+q*8+j][n=n0*16+m]
    short8 bg[4][2], bbf[4][2];
    #pragma unroll
    for (int n0 = 0; n0 < 4; ++n0) {
        const int n = n0 * 16 + m;
        #pragma unroll
        for (int kh = 0; kh < 2; ++kh) {
            bg [n0][kh] = *(const short8*)(wg_bf + n * EMB + kh * 32 + q * 8);
            bbf[n0][kh] = *(const short8*)(wb_bf + n * EMB + kh * 32 + q * 8);
        }
    }
    float bgc[4], bbc[4];
    #pragma unroll
    for (int n0 = 0; n0 < 4; ++n0) { bgc[n0] = gb[n0 * 16 + m]; bbc[n0] = bb[n0 * 16 + m]; }

    // ---- A fragments: rows t*16 .. t*16+15
    const size_t base = (size_t)t * 16 * EMB;
    const int ao = m * EMB + q * 8;
    short8 as0 = *(const short8*)(side_bf + base + ao);
    short8 as1 = *(const short8*)(side_bf + base + ao + 32);
    short8 ae0 = *(const short8*)(ego_bf  + base + ao);
    short8 ae1 = *(const short8*)(ego_bf  + base + ao + 32);
    short8 ap0, ap1;
    #pragma unroll
    for (int jj = 0; jj < 8; ++jj) {
        ap0[jj] = (short)f2bf(bf2f((unsigned short)as0[jj]) * bf2f((unsigned short)ae0[jj]));
        ap1[jj] = (short)f2bf(bf2f((unsigned short)as1[jj]) * bf2f((unsigned short)ae1[jj]));
    }

    // ---- MFMAs
    float4v c1[4], c2[4];
    #pragma unroll
    for (int n0 = 0; n0 < 4; ++n0) { c1[n0] = (float4v)0.f; c2[n0] = (float4v)0.f; }
    #pragma unroll
    for (int n0 = 0; n0 < 4; ++n0) {
        c1[n0] = __builtin_amdgcn_mfma_f32_16x16x32_bf16(as0, bg [n0][0], c1[n0], 0, 0, 0);
        c1[n0] = __builtin_amdgcn_mfma_f32_16x16x32_bf16(as1, bg [n0][1], c1[n0], 0, 0, 0);
        c2[n0] = __builtin_amdgcn_mfma_f32_16x16x32_bf16(ap0, bbf[n0][0], c2[n0], 0, 0, 0);
        c2[n0] = __builtin_amdgcn_mfma_f32_16x16x32_bf16(ap1, bbf[n0][1], c2[n0], 0, 0, 0);
    }

    // ---- epilogue: bias + leaky + ego update + L2 norm
    float eg[4][4];          // [n0][reg]; row = t*16 + q*4 + reg, col = n0*16 + m
    float ss[4] = {0.f, 0.f, 0.f, 0.f};
    #pragma unroll
    for (int n0 = 0; n0 < 4; ++n0) {
        #pragma unroll
        for (int r = 0; r < 4; ++r) {
            float a1 = c1[n0][r] + bgc[n0];
            float a2 = c2[n0][r] + bbc[n0];
            float v1 = a1 > 0.f ? a1 : 0.01f * a1;
            float v2 = a2 > 0.f ? a2 : 0.01f * a2;
            float e = v1 + v2;
            eg[n0][r] = e;
            ss[r] += e * e;
        }
    }
    #pragma unroll
    for (int r = 0; r < 4; ++r) {
        float s = ss[r];
        s += __shfl_xor(s, 1, 64);
        s += __shfl_xor(s, 2, 64);
        s += __shfl_xor(s, 4, 64);
        s += __shfl_xor(s, 8, 64);
        ss[r] = 1.0f / fmaxf(sqrtf(s), 1e-12f);
    }
    #pragma unroll
    for (int r = 0; r < 4; ++r) {
        int row = t * 16 + q * 4 + r;
        #pragma unroll
        for (int n0 = 0; n0 < 4; ++n0) {
            int col = n0 * 16 + m;
            ego_bf[(size_t)row * EMB + col] = f2bf(eg[n0][r]);
            out[(size_t)row * 256 + out_col0 + col] = eg[n0][r] * ss[r];
        }
    }
}

extern "C" void kernel_launch(void* const* d_in, const int* in_sizes, int n_in,
                              void* d_out, int out_size, void* d_ws, size_t ws_size,
                              hipStream_t stream)
{
    const int*   rows = (const int*)  d_in[0];
    const int*   cols = (const int*)  d_in[1];
    const float* vals = (const float*)d_in[2];
    const float* ue   = (const float*)d_in[3];
    const float* ie   = (const float*)d_in[4];
    const float* gw   = (const float*)d_in[5];
    const float* gb   = (const float*)d_in[6];
    const float* bw   = (const float*)d_in[7];
    const float* bb   = (const float*)d_in[8];
    float* out = (float*)d_out;

    // ---- workspace layout (~58.3 MB) ----
    char* p = (char*)d_ws;
    unsigned short* ego_bf  = (unsigned short*)p;  p += (size_t)NNODES * EMB * 2;  // 19.2 MB
    unsigned short* side_bf = (unsigned short*)p;  p += (size_t)NNODES * EMB * 2;  // 19.2 MB
    int2*  edges  = (int2*)p;    p += (size_t)NEDGES * 8;                          // 19.2 MB
    int*   rowptr = (int*)p;     p += ((size_t)NNODES + 4) * 4;                    // 0.6 MB
    unsigned short* wg_bf = (unsigned short*)p;  p += (size_t)NLAYERS * EMB * EMB * 2;
    unsigned short* wb_bf = (unsigned short*)p;  p += (size_t)NLAYERS * EMB * EMB * 2;
    // build scratch aliased into side region (10.2 MB < 19.2 MB; side rewritten each layer)
    int* deg   = (int*)side_bf;
    int* rank  = (int*)side_bf + NNODES;
    int* bsum  = (int*)side_bf + NNODES + NEDGES;
    int* bscan = bsum + 256;

    // ---- CSR build ----
    hipMemsetAsync(deg, 0, (size_t)NNODES * 4, stream);
    hist_rank_kernel<<<(NEDGES + 255) / 256, 256, 0, stream>>>(rows, deg, rank);
    block_sum_kernel<<<NSCAN_BLOCKS, 256, 0, stream>>>(deg, bsum);
    scan_partials_kernel<<<1, 256, 0, stream>>>(bsum, bscan, rowptr);
    block_scan_kernel<<<NSCAN_BLOCKS, 256, 0, stream>>>(deg, bscan, rowptr);
    scatter_kernel<<<(NEDGES + 255) / 256, 256, 0, stream>>>(
        rows, cols, vals, rank, rowptr, edges);

    wconv_kernel<<<(NLAYERS * EMB * EMB + 255) / 256, 256, 0, stream>>>(gw, bw, wg_bf, wb_bf);
    init_kernel<<<(NNODES * 16 + 255) / 256, 256, 0, stream>>>(ue, ie, ego_bf, out);

    for (int l = 0; l < NLAYERS; ++l) {
        spmm_pull<<<NNODES / 16, 256, 0, stream>>>(rowptr, edges, ego_bf, side_bf);
        dense_mfma<<<(NTILES + 3) / 4, 256, 0, stream>>>(
            side_bf, ego_bf,
            wg_bf + l * EMB * EMB, wb_bf + l * EMB * EMB,
            gb + l * EMB, bb + l * EMB,
            out, 64 * (l + 1));
    }
}